// Round 11
// baseline (3286.143 us; speedup 1.0000x reference)
//
#include <hip/hip_runtime.h>
#include <hip/hip_bf16.h>
#include <math.h>

#define BN_EPS 1e-3f
#define SLOPE  0.1f
#define TEMP   5.0f
#define DDIM   3136            // 64 * 49

typedef __attribute__((ext_vector_type(8))) short bf16x8;
typedef __attribute__((ext_vector_type(4))) float f32x4;

static __device__ __forceinline__ short f2b(float f) {
  __hip_bfloat16 h = __float2bfloat16(f);
  return *reinterpret_cast<short*>(&h);
}

// ---- workspace layout (in float slots) ----
#define W2B_OFF   0u                           // w2b bf16 204800 shorts
#define W1B_OFF   102400u                      // w1b bf16 4096 shorts
#define DB_OFF    104448u                      // data bf16 [8192][3136]
#define DB_SZ     (8192u*3136u/2u)             // 12845056
#define DT_OFF    (DB_OFF + DB_SZ)             // dataT bf16 [3136][8192]
#define DT_SZ     (8192u*3136u/2u)
#define MUB_OFF   (DT_OFF + DT_SZ)             // mu bf16 [112][3136]
#define MUB_SZ    (112u*3136u/2u)              // 175616
#define CMS_OFF   (MUB_OFF + MUB_SZ)           // cms bf16 [16][3136][112]
#define CMS_SZ    (16u*3136u*112u/2u)          // 2809856
#define RT_OFF    (CMS_OFF + CMS_SZ)           // rT bf16 [112][8192]
#define RT_SZ     (112u*8192u/2u)              // 458752
#define CRB_OFF   (RT_OFF + RT_SZ)             // crb fp32 [12][128]
#define CNT_OFF   (CRB_OFF + 12u*128u)         // cnt u32 [64]

// ---------------------------------------------------------------------------
// Weight prep: w2 -> bf16 MFMA-frag order; w1 -> bf16 frag order.
// ---------------------------------------------------------------------------
__global__ __launch_bounds__(256) void k_wprep(const float* __restrict__ w2,
                                               const float* __restrict__ w1,
                                               __hip_bfloat16* __restrict__ w2b,
                                               __hip_bfloat16* __restrict__ w1b) {
  int idx = blockIdx.x * 256 + threadIdx.x;
  if (idx < 204800) {
    int ci   = idx & 31;
    int lr   = (idx >> 5) & 15;
    int rest = idx >> 9;
    int kk   = rest % 100;
    int oct  = rest / 100;
    int oc   = oct * 16 + lr;
    int tap  = kk >> 2;
    int c    = ((kk & 3) << 5) + ci;
    w2b[idx] = __float2bfloat16(w2[(oc * 128 + c) * 25 + tap]);
  } else {
    int j = idx - 204800;
    if (j < 4096) {
      int k   = j & 31;
      int lr  = (j >> 5) & 15;
      int oct = j >> 9;
      int oc  = oct * 16 + lr;
      float v = (k < 25) ? w1[oc * 25 + k] : 0.f;
      w1b[j] = __float2bfloat16(v);
    }
  }
}

// ---------------------------------------------------------------------------
// Fused conv1 (MFMA, xs staged bf16) -> h1 LDS bf16 ((ip>>1)&7 swizzle)
// -> conv2 (MFMA, 4-wave K-split) -> BN2+LReLU+L2norm -> db.  (r10 version)
// ---------------------------------------------------------------------------
__global__ __launch_bounds__(256) void k_conv(
    const float* __restrict__ x,
    const __hip_bfloat16* __restrict__ w1bh, const float* __restrict__ b1,
    const float* __restrict__ g1,  const float* __restrict__ be1,
    const float* __restrict__ mn1, const float* __restrict__ vr1,
    const __hip_bfloat16* __restrict__ w2bh, const float* __restrict__ b2,
    const float* __restrict__ g2,  const float* __restrict__ be2,
    const float* __restrict__ mn2, const float* __restrict__ vr2,
    __hip_bfloat16* __restrict__ db) {
  __shared__ unsigned short xsb[1024];              // padded 32x32 image, bf16
  __shared__ float nrm[4];
  __shared__ __align__(16) __hip_bfloat16 h1s[197 * 128];  // 50432 B

  const int t    = threadIdx.x;
  const int img  = blockIdx.x;
  const int lane = t & 63;
  const int wv   = t >> 6;
  const int lr   = lane & 15;
  const int kg   = lane >> 4;
  const short* w2b = (const short*)w2bh;
  const short* w1b = (const short*)w1bh;

  float a1v[8], s1v[8];
#pragma unroll
  for (int r = 0; r < 4; ++r) {
    int oc = wv * 32 + kg * 4 + r;
    float a = g1[oc] * rsqrtf(vr1[oc] + BN_EPS);
    a1v[r] = a; s1v[r] = b1[oc] * a + be1[oc] - mn1[oc] * a;
    int oc2 = oc + 16;
    float a2_ = g1[oc2] * rsqrtf(vr1[oc2] + BN_EPS);
    a1v[4 + r] = a2_; s1v[4 + r] = b1[oc2] * a2_ + be1[oc2] - mn1[oc2] * a2_;
  }
  float a2v[4], s2v[4];
#pragma unroll
  for (int r = 0; r < 4; ++r) {
    int oc = wv * 16 + kg * 4 + r;
    float a = g2[oc] * rsqrtf(vr2[oc] + BN_EPS);
    a2v[r] = a; s2v[r] = b2[oc] * a + be2[oc] - mn2[oc] * a;
  }

  for (int i = t; i < 1024; i += 256) xsb[i] = 0;
  if (t < 64) ((unsigned*)(h1s + 196 * 128))[t] = 0u;   // zero row 196
  __syncthreads();
  const float* xi = x + (size_t)img * 784;
  for (int i = t; i < 784; i += 256) {
    int yy = i / 28, xx = i % 28;
    xsb[(yy + 2) * 32 + (xx + 2)] = (unsigned short)f2b(xi[i]);
  }
  __syncthreads();

  {
    bf16x8 a0 = *(const bf16x8*)(w1b + (2 * wv) * 512 + lr * 32 + kg * 8);
    bf16x8 a1 = *(const bf16x8*)(w1b + (2 * wv + 1) * 512 + lr * 32 + kg * 8);
    for (int pt = 0; pt < 13; ++pt) {
      const int px  = pt * 16 + lr;
      const int pxc = (px < 196) ? px : 195;
      const int oy  = pxc / 14, ox = pxc - 14 * (pxc / 14);
      const unsigned short* xb = xsb + (2 * oy) * 32 + 2 * ox;
      short bs[8];
#pragma unroll
      for (int j = 0; j < 8; ++j) {
        int k   = kg * 8 + j;
        int tap = (k < 25) ? k : 0;
        int kh  = tap / 5, kw = tap - 5 * (tap / 5);
        bs[j] = (short)xb[kh * 32 + kw];
      }
      bf16x8 b;
#pragma unroll
      for (int j = 0; j < 8; ++j) b[j] = bs[j];
      f32x4 c0 = {0.f, 0.f, 0.f, 0.f}, c1 = {0.f, 0.f, 0.f, 0.f};
      c0 = __builtin_amdgcn_mfma_f32_16x16x32_bf16(a0, b, c0, 0, 0, 0);
      c1 = __builtin_amdgcn_mfma_f32_16x16x32_bf16(a1, b, c1, 0, 0, 0);
      if (px < 196) {
        const int swz = ((px >> 1) & 7) << 4;
        float v[4], u[4];
#pragma unroll
        for (int r = 0; r < 4; ++r) {
          float h = c0[r] * a1v[r] + s1v[r];
          v[r] = (h >= 0.f) ? h : SLOPE * h;
          float h2 = c1[r] * a1v[4 + r] + s1v[4 + r];
          u[r] = (h2 >= 0.f) ? h2 : SLOPE * h2;
        }
        unsigned w0lo = (unsigned)(unsigned short)f2b(v[0]) |
                        ((unsigned)(unsigned short)f2b(v[1]) << 16);
        unsigned w0hi = (unsigned)(unsigned short)f2b(v[2]) |
                        ((unsigned)(unsigned short)f2b(v[3]) << 16);
        unsigned w1lo = (unsigned)(unsigned short)f2b(u[0]) |
                        ((unsigned)(unsigned short)f2b(u[1]) << 16);
        unsigned w1hi = (unsigned)(unsigned short)f2b(u[2]) |
                        ((unsigned)(unsigned short)f2b(u[3]) << 16);
        char* base = (char*)h1s + px * 256;
        const int o0 = ((wv * 32 + kg * 4) * 2) ^ swz;
        const int o1 = ((wv * 32 + 16 + kg * 4) * 2) ^ swz;
        *(uint2*)(base + o0) = make_uint2(w0lo, w0hi);
        *(uint2*)(base + o1) = make_uint2(w1lo, w1hi);
      }
    }
  }
  __syncthreads();

  const int woff  = lr * 32 + kg * 8;
  const int kgoff = kg << 4;
  int pxA[4], oyA[4], oxA[4];
#pragma unroll
  for (int pt = 0; pt < 4; ++pt) {
    int p = pt * 16 + lr;
    pxA[pt] = p;
    oyA[pt] = p / 7;
    oxA[pt] = p - 7 * oyA[pt];
  }

  f32x4 acc[4][4];
#pragma unroll
  for (int oct = 0; oct < 4; ++oct)
#pragma unroll
    for (int pt = 0; pt < 4; ++pt) acc[oct][pt] = (f32x4){0.f, 0.f, 0.f, 0.f};

  const int s0 = 25 * wv, s1e = s0 + 25;
  int curtap = -1;
  int rowB[4], rowS[4];

  auto loadk = [&](int kk, bf16x8* areg, bf16x8* breg) {
    int tap = kk >> 2;
    if (tap != curtap) {
      curtap = tap;
      int kh = tap / 5, kw = tap - 5 * (tap / 5);
#pragma unroll
      for (int pt = 0; pt < 4; ++pt) {
        int iy = 2 * oyA[pt] - 2 + kh;
        int ix = 2 * oxA[pt] - 2 + kw;
        bool val = (pxA[pt] < 49) & ((unsigned)iy < 14u) & ((unsigned)ix < 14u);
        int ip = val ? iy * 14 + ix : 196;
        rowB[pt] = ip * 256;
        rowS[pt] = ((ip >> 1) & 7) << 4;
      }
    }
    int c01 = (kk & 3) << 6;
#pragma unroll
    for (int oct = 0; oct < 4; ++oct)
      areg[oct] = *(const bf16x8*)(w2b + ((oct * 100 + kk) << 9) + woff);
#pragma unroll
    for (int pt = 0; pt < 4; ++pt)
      breg[pt] = *(const bf16x8*)((const char*)h1s + rowB[pt] +
                                  ((c01 | kgoff) ^ rowS[pt]));
  };

  bf16x8 a[4], b[4], an[4], bn_[4];
  loadk(s0, a, b);
  for (int kk = s0; kk < s1e; ++kk) {
    if (kk + 1 < s1e) loadk(kk + 1, an, bn_);
#pragma unroll
    for (int oct = 0; oct < 4; ++oct)
#pragma unroll
      for (int pt = 0; pt < 4; ++pt)
        acc[oct][pt] = __builtin_amdgcn_mfma_f32_16x16x32_bf16(a[oct], b[pt],
                                                               acc[oct][pt], 0, 0, 0);
#pragma unroll
    for (int q = 0; q < 4; ++q) { a[q] = an[q]; b[q] = bn_[q]; }
  }
  __syncthreads();

  float* red = (float*)h1s;
  if (wv != 0) {
#pragma unroll
    for (int oct = 0; oct < 4; ++oct)
#pragma unroll
      for (int pt = 0; pt < 4; ++pt)
#pragma unroll
        for (int r = 0; r < 4; ++r)
          red[(wv - 1) * 4096 + ((oct * 4 + pt) * 4 + r) * 64 + lane] =
              acc[oct][pt][r];
  }
  __syncthreads();
  if (wv == 0) {
#pragma unroll
    for (int oct = 0; oct < 4; ++oct)
#pragma unroll
      for (int pt = 0; pt < 4; ++pt)
#pragma unroll
        for (int r = 0; r < 4; ++r) {
          const int i = (oct * 4 + pt) * 4 + r;
          float v = acc[oct][pt][r] + red[i * 64 + lane] +
                    red[4096 + i * 64 + lane] + red[8192 + i * 64 + lane];
          red[i * 64 + lane] = v;
        }
  }
  __syncthreads();

  float outv[16];
  float ss = 0.f;
#pragma unroll
  for (int pt = 0; pt < 4; ++pt) {
#pragma unroll
    for (int r = 0; r < 4; ++r) {
      const int i = ((wv * 4 + pt) * 4 + r);
      float v = red[i * 64 + lane];
      v = v * a2v[r] + s2v[r];
      v = (v >= 0.f) ? v : SLOPE * v;
      outv[pt * 4 + r] = v;
      if (pxA[pt] < 49) ss += v * v;
    }
  }
#pragma unroll
  for (int m = 1; m < 64; m <<= 1) ss += __shfl_xor(ss, m, 64);
  if (lane == 0) nrm[wv] = ss;
  __syncthreads();
  const float invn = rsqrtf(nrm[0] + nrm[1] + nrm[2] + nrm[3]);
  __hip_bfloat16* dro = db + (size_t)img * DDIM;
#pragma unroll
  for (int pt = 0; pt < 4; ++pt) {
    if (pxA[pt] < 49) {
#pragma unroll
      for (int r = 0; r < 4; ++r) {
        const int oc = wv * 16 + kg * 4 + r;
        dro[oc * 49 + pxA[pt]] = __float2bfloat16(outv[pt * 4 + r] * invn);
      }
    }
  }
}

// ---------------------------------------------------------------------------
// 64x64 tiled transpose: dT[d][img] = db[img][d]   (NT both streams)
// ---------------------------------------------------------------------------
__global__ __launch_bounds__(256) void k_tr(const __hip_bfloat16* __restrict__ dbh,
                                            __hip_bfloat16* __restrict__ dTh) {
  __shared__ short tile[64][72];
  const int t   = threadIdx.x;
  const int i   = t >> 2;
  const int seg = t & 3;
  const size_t img0 = (size_t)blockIdx.x * 64;
  const size_t d0   = (size_t)blockIdx.y * 64;
  const short* src = (const short*)dbh + (img0 + i) * DDIM + d0 + seg * 16;
  bf16x8 v0 = __builtin_nontemporal_load((const bf16x8*)src);
  bf16x8 v1 = __builtin_nontemporal_load((const bf16x8*)(src + 8));
  *(bf16x8*)&tile[i][seg * 16]     = v0;
  *(bf16x8*)&tile[i][seg * 16 + 8] = v1;
  __syncthreads();
  short tmp[16];
#pragma unroll
  for (int k = 0; k < 16; ++k) tmp[k] = tile[seg * 16 + k][i];
  short* dst = (short*)dTh + (d0 + i) * 8192 + img0 + seg * 16;
  __builtin_nontemporal_store(*(bf16x8*)tmp, (bf16x8*)dst);
  __builtin_nontemporal_store(*((bf16x8*)tmp + 1), (bf16x8*)(dst + 8));
}

// ---------------------------------------------------------------------------
// mu bf16 init (rows 100-111 zero) + rT pad rows + crb + cnt zero.
// ---------------------------------------------------------------------------
__global__ __launch_bounds__(256) void k_muinit(const float* __restrict__ mu0,
                                                __hip_bfloat16* __restrict__ mub,
                                                __hip_bfloat16* __restrict__ rT,
                                                float* __restrict__ crb,
                                                unsigned* __restrict__ cnt) {
  int idx = blockIdx.x * 256 + threadIdx.x;
  if (idx < 112 * DDIM) {
    int j = idx / DDIM, d = idx - j * DDIM;
    float v = (j < 100) ? mu0[j * DDIM + d] : 0.f;
    mub[idx] = __float2bfloat16(v);
  }
  if (idx < 12 * 8192)
    rT[(size_t)100 * 8192 + idx] = __float2bfloat16(0.f);
  if (idx < 12 * 128) crb[idx] = 0.f;
  if (idx < 64) cnt[idx] = 0u;
}

// ---------------------------------------------------------------------------
// Fused dist (MFMA) + softmax + cluster_r.  (r5/r10 shape: 512 blocks x 512
// thr, 16 rows, 8-way K-split.)  NT loads on data stream; packed rT stores.
// ---------------------------------------------------------------------------
__global__ __launch_bounds__(512) void k_dsm(
    const __hip_bfloat16* __restrict__ data,
    const __hip_bfloat16* __restrict__ mu,
    __hip_bfloat16* __restrict__ rT,          // [112][8192]
    float* __restrict__ cr,                   // [128] slot for this iter
    float* __restrict__ outr,                 // final: [8192][100]
    float* __restrict__ outd,                 // final: [8192][100]
    int final_flag) {
  __shared__ float red[7][64][29];
  const int t    = threadIdx.x;
  const int lane = t & 63;
  const int wv   = t >> 6;                    // 0..7
  const int rowbase = blockIdx.x * 16;
  const int s0 = (98 * wv) >> 3;
  const int s1 = (98 * (wv + 1)) >> 3;
  const int lr = lane & 15;
  const int kg = lane >> 4;

  const __hip_bfloat16* arow = data + (size_t)(rowbase + lr) * DDIM + kg * 8;
  const __hip_bfloat16* brow = mu + (size_t)lr * DDIM + kg * 8;

  f32x4 acc[7];
#pragma unroll
  for (int i = 0; i < 7; ++i) acc[i] = (f32x4){0.f, 0.f, 0.f, 0.f};

  bf16x8 a, b[7], an, bn_[7];
  {
    const int k0 = s0 * 32;
    a = __builtin_nontemporal_load((const bf16x8*)(arow + k0));
#pragma unroll
    for (int tl = 0; tl < 7; ++tl)
      b[tl] = *(const bf16x8*)(brow + (size_t)tl * 16 * DDIM + k0);
  }
  for (int s = s0; s < s1; ++s) {
    if (s + 1 < s1) {
      const int k1 = (s + 1) * 32;
      an = __builtin_nontemporal_load((const bf16x8*)(arow + k1));
#pragma unroll
      for (int tl = 0; tl < 7; ++tl)
        bn_[tl] = *(const bf16x8*)(brow + (size_t)tl * 16 * DDIM + k1);
    }
#pragma unroll
    for (int tl = 0; tl < 7; ++tl)
      acc[tl] = __builtin_amdgcn_mfma_f32_16x16x32_bf16(a, b[tl], acc[tl], 0, 0, 0);
    a = an;
#pragma unroll
    for (int tl = 0; tl < 7; ++tl) b[tl] = bn_[tl];
  }

  if (wv != 0) {
#pragma unroll
    for (int tl = 0; tl < 7; ++tl)
#pragma unroll
      for (int r = 0; r < 4; ++r) red[wv - 1][lane][tl * 4 + r] = acc[tl][r];
  }
  __syncthreads();
  if (wv != 0) return;

#pragma unroll
  for (int tl = 0; tl < 7; ++tl)
#pragma unroll
    for (int r = 0; r < 4; ++r) {
      float v = acc[tl][r];
#pragma unroll
      for (int bk = 0; bk < 7; ++bk) v += red[bk][lane][tl * 4 + r];
      acc[tl][r] = v;
    }

  if (final_flag) {
#pragma unroll
    for (int tl = 0; tl < 7; ++tl) {
      const int col = tl * 16 + lr;
      if (col < 100) {
#pragma unroll
        for (int r = 0; r < 4; ++r)
          outd[(size_t)(rowbase + kg * 4 + r) * 100 + col] = acc[tl][r];
      }
    }
  }

#pragma unroll
  for (int r = 0; r < 4; ++r) {
    float m = -1e30f;
#pragma unroll
    for (int tl = 0; tl < 7; ++tl) {
      const bool valid = (tl < 6) || (lr < 4);
      m = fmaxf(m, valid ? acc[tl][r] : -1e30f);
    }
    m = fmaxf(m, __shfl_xor(m, 1, 64));
    m = fmaxf(m, __shfl_xor(m, 2, 64));
    m = fmaxf(m, __shfl_xor(m, 4, 64));
    m = fmaxf(m, __shfl_xor(m, 8, 64));
    float s = 0.f;
    float e[7];
#pragma unroll
    for (int tl = 0; tl < 7; ++tl) {
      const bool valid = (tl < 6) || (lr < 4);
      e[tl] = valid ? __expf(TEMP * (acc[tl][r] - m)) : 0.f;
      s += e[tl];
    }
    s += __shfl_xor(s, 1, 64);
    s += __shfl_xor(s, 2, 64);
    s += __shfl_xor(s, 4, 64);
    s += __shfl_xor(s, 8, 64);
    const float inv = 1.f / s;
#pragma unroll
    for (int tl = 0; tl < 7; ++tl) acc[tl][r] = e[tl] * inv;
  }

  if (final_flag) {
#pragma unroll
    for (int tl = 0; tl < 7; ++tl) {
      const int col = tl * 16 + lr;
      if (col < 100) {
#pragma unroll
        for (int r = 0; r < 4; ++r)
          outr[(size_t)(rowbase + kg * 4 + r) * 100 + col] = acc[tl][r];
      }
    }
    return;
  }

#pragma unroll
  for (int tl = 0; tl < 7; ++tl) {
    const int col = tl * 16 + lr;
    if (col < 100) {
      unsigned lo = (unsigned)(unsigned short)f2b(acc[tl][0]) |
                    ((unsigned)(unsigned short)f2b(acc[tl][1]) << 16);
      unsigned hi = (unsigned)(unsigned short)f2b(acc[tl][2]) |
                    ((unsigned)(unsigned short)f2b(acc[tl][3]) << 16);
      *(uint2*)((short*)rT + (size_t)col * 8192 + rowbase + kg * 4) =
          make_uint2(lo, hi);
    }
  }
  float csum[7];
#pragma unroll
  for (int tl = 0; tl < 7; ++tl) {
    float cs = acc[tl][0] + acc[tl][1] + acc[tl][2] + acc[tl][3];
    cs += __shfl_xor(cs, 16, 64);
    cs += __shfl_xor(cs, 32, 64);
    csum[tl] = cs;
  }
  if (lane < 16) {
#pragma unroll
    for (int tl = 0; tl < 7; ++tl) {
      const int col = tl * 16 + lane;
      if (col < 100) atomicAdd(cr + col, csum[tl]);
    }
  }
}

// ---------------------------------------------------------------------------
// cms[split][d][j] (bf16) = partial dataT @ rT over K-chunk of 512
// (GEMM identical to r10), THEN the 16th-finishing block per d-range reduces
// the 16 splits, divides by cr, and writes mub + muf (k_upd merged in).
// grid (49, 16); block = 64 d-rows (4 waves x 16 rows).
// ---------------------------------------------------------------------------
__global__ __launch_bounds__(256) void k_mu(
    const __hip_bfloat16* __restrict__ dataT,  // [3136][8192]
    const __hip_bfloat16* __restrict__ rT,     // [112][8192]
    __hip_bfloat16* __restrict__ cms,          // [16][3136][112]
    const float* __restrict__ cr,              // [128] this iteration
    float* __restrict__ muf,                   // fp32 mu -> d_out (every iter)
    __hip_bfloat16* __restrict__ mub,          // [112][3136]
    unsigned* __restrict__ cnt) {              // [64] completion counters
  __shared__ float tile[64][113];
  __shared__ unsigned done;
  const int t    = threadIdx.x;
  const int lane = t & 63;
  const int wv   = t >> 6;
  const int mbase = blockIdx.x * 64 + wv * 16;
  const int kbase = blockIdx.y * 512;
  const int lr = lane & 15;
  const int kg = lane >> 4;

  const __hip_bfloat16* arow = dataT + (size_t)(mbase + lr) * 8192 + kbase + kg * 8;
  const __hip_bfloat16* brow = rT + (size_t)lr * 8192 + kbase + kg * 8;

  f32x4 acc[7];
#pragma unroll
  for (int i = 0; i < 7; ++i) acc[i] = (f32x4){0.f, 0.f, 0.f, 0.f};

  bf16x8 a, b[7], an, bn_[7];
  a = __builtin_nontemporal_load((const bf16x8*)arow);
#pragma unroll
  for (int tl = 0; tl < 7; ++tl)
    b[tl] = *(const bf16x8*)(brow + (size_t)tl * 16 * 8192);
  for (int s = 0; s < 16; ++s) {
    if (s + 1 < 16) {
      const int k1 = (s + 1) * 32;
      an = __builtin_nontemporal_load((const bf16x8*)(arow + k1));
#pragma unroll
      for (int tl = 0; tl < 7; ++tl)
        bn_[tl] = *(const bf16x8*)(brow + (size_t)tl * 16 * 8192 + k1);
    }
#pragma unroll
    for (int tl = 0; tl < 7; ++tl)
      acc[tl] = __builtin_amdgcn_mfma_f32_16x16x32_bf16(a, b[tl], acc[tl], 0, 0, 0);
    a = an;
#pragma unroll
    for (int tl = 0; tl < 7; ++tl) b[tl] = bn_[tl];
  }

  __hip_bfloat16* dst = cms + (size_t)blockIdx.y * (3136u * 112u);
#pragma unroll
  for (int tl = 0; tl < 7; ++tl) {
    const int col = tl * 16 + lr;
#pragma unroll
    for (int r = 0; r < 4; ++r)
      dst[(size_t)(mbase + kg * 4 + r) * 112 + col] = __float2bfloat16(acc[tl][r]);
  }

  // ---- completion protocol: last of the 16 K-split blocks for this d-range
  // reduces + divides + writes mu (merged k_upd) ----
  __threadfence();                         // make this thread's cms writes
  __syncthreads();                         // device-visible before the atomic
  if (t == 0) done = atomicAdd(cnt + blockIdx.x, 1u);
  __syncthreads();
  if (done != 15) return;                  // uniform across block
  __threadfence();                         // acquire: order subsequent reads
  if (t == 0) cnt[blockIdx.x] = 0u;        // reset for next iteration

  const int d0 = blockIdx.x * 64;
  for (int e = t; e < 64 * 112; e += 256) {
    int dd = e / 112, jj = e - dd * 112;
    const __hip_bfloat16* p = cms + (size_t)(d0 + dd) * 112 + jj;
    float v = 0.f;
#pragma unroll
    for (int s2 = 0; s2 < 16; ++s2)
      v += __bfloat162float(p[(size_t)s2 * (3136u * 112u)]);
    tile[dd][jj] = v;
  }
  __syncthreads();
  for (int e = t; e < 100 * 64; e += 256) {
    int jj = e >> 6, dd = e & 63;
    float v = tile[dd][jj] / cr[jj];
    muf[(size_t)jj * DDIM + d0 + dd] = v;
    mub[(size_t)jj * DDIM + d0 + dd] = __float2bfloat16(v);
  }
}

// ---------------------------------------------------------------------------
extern "C" void kernel_launch(void* const* d_in, const int* in_sizes, int n_in,
                              void* d_out, int out_size, void* d_ws, size_t ws_size,
                              hipStream_t stream) {
  const float* x   = (const float*)d_in[0];
  const float* w1  = (const float*)d_in[1];
  const float* b1  = (const float*)d_in[2];
  const float* g1  = (const float*)d_in[3];
  const float* be1 = (const float*)d_in[4];
  const float* mn1 = (const float*)d_in[5];
  const float* vr1 = (const float*)d_in[6];
  const float* w2  = (const float*)d_in[7];
  const float* b2  = (const float*)d_in[8];
  const float* g2  = (const float*)d_in[9];
  const float* be2 = (const float*)d_in[10];
  const float* mn2 = (const float*)d_in[11];
  const float* vr2 = (const float*)d_in[12];
  const float* mu0 = (const float*)d_in[13];

  float* ws = (float*)d_ws;
  __hip_bfloat16* w2b = (__hip_bfloat16*)(ws + W2B_OFF);
  __hip_bfloat16* w1b = (__hip_bfloat16*)(ws + W1B_OFF);
  __hip_bfloat16* db  = (__hip_bfloat16*)(ws + DB_OFF);
  __hip_bfloat16* dT  = (__hip_bfloat16*)(ws + DT_OFF);
  __hip_bfloat16* mub = (__hip_bfloat16*)(ws + MUB_OFF);
  __hip_bfloat16* cms = (__hip_bfloat16*)(ws + CMS_OFF);
  __hip_bfloat16* rT  = (__hip_bfloat16*)(ws + RT_OFF);
  float*          crb = ws + CRB_OFF;               // [12][128]
  unsigned*       cnt = (unsigned*)(ws + CNT_OFF);  // [64]
  float*          out = (float*)d_out;

  k_wprep<<<816, 256, 0, stream>>>(w2, w1, w2b, w1b);
  k_conv<<<8192, 256, 0, stream>>>(x, w1b, b1, g1, be1, mn1, vr1,
                                   w2b, b2, g2, be2, mn2, vr2, db);
  k_tr<<<dim3(128, 49), 256, 0, stream>>>(db, dT);
  k_muinit<<<1372, 256, 0, stream>>>(mu0, mub, rT, crb, cnt);

  for (int it = 0; it < 11; ++it) {
    k_dsm<<<512, 512, 0, stream>>>(db, mub, rT, crb + it * 128,
                                   nullptr, nullptr, 0);
    k_mu<<<dim3(49, 16), 256, 0, stream>>>(dT, rT, cms, crb + it * 128,
                                           out, mub, cnt);
  }

  k_dsm<<<512, 512, 0, stream>>>(db, mub, rT, crb + 11 * 128,
                                 out + 313600, out + 1132800, 1);
}

// Round 12
// 1850.815 us; speedup vs baseline: 1.7755x; 1.7755x over previous
//
#include <hip/hip_runtime.h>
#include <hip/hip_bf16.h>
#include <math.h>

#define BN_EPS 1e-3f
#define SLOPE  0.1f
#define TEMP   5.0f
#define DDIM   3136            // 64 * 49

typedef __attribute__((ext_vector_type(8))) short bf16x8;
typedef __attribute__((ext_vector_type(4))) float f32x4;

static __device__ __forceinline__ short f2b(float f) {
  __hip_bfloat16 h = __float2bfloat16(f);
  return *reinterpret_cast<short*>(&h);
}

// Gray-code swizzle key: bijective on 8 consecutive values at stride 1 AND 2.
static __device__ __forceinline__ int swz8(int ip) {
  return ((ip ^ (ip >> 1)) & 7) << 4;
}

// ---- workspace layout (in float slots) ----
#define W2B_OFF   0u                           // w2b bf16 204800 shorts
#define W1B_OFF   102400u                      // w1b bf16 4096 shorts
#define DB_OFF    104448u                      // data bf16 [8192][3136]
#define DB_SZ     (8192u*3136u/2u)             // 12845056
#define DT_OFF    (DB_OFF + DB_SZ)             // dataT bf16 [3136][8192]
#define DT_SZ     (8192u*3136u/2u)
#define MUB_OFF   (DT_OFF + DT_SZ)             // mu bf16 [112][3136]
#define MUB_SZ    (112u*3136u/2u)              // 175616
#define CMS_OFF   (MUB_OFF + MUB_SZ)           // cms bf16 [16][3136][112]
#define CMS_SZ    (16u*3136u*112u/2u)          // 2809856
#define RT_OFF    (CMS_OFF + CMS_SZ)           // rT bf16 [112][8192]
#define RT_SZ     (112u*8192u/2u)              // 458752
#define CRB_OFF   (RT_OFF + RT_SZ)             // crb fp32 [12][128]

// ---------------------------------------------------------------------------
// Weight prep: w2 -> bf16 MFMA-frag order; w1 -> bf16 frag order.
// ---------------------------------------------------------------------------
__global__ __launch_bounds__(256) void k_wprep(const float* __restrict__ w2,
                                               const float* __restrict__ w1,
                                               __hip_bfloat16* __restrict__ w2b,
                                               __hip_bfloat16* __restrict__ w1b) {
  int idx = blockIdx.x * 256 + threadIdx.x;
  if (idx < 204800) {
    int ci   = idx & 31;
    int lr   = (idx >> 5) & 15;
    int rest = idx >> 9;
    int kk   = rest % 100;
    int oct  = rest / 100;
    int oc   = oct * 16 + lr;
    int tap  = kk >> 2;
    int c    = ((kk & 3) << 5) + ci;
    w2b[idx] = __float2bfloat16(w2[(oc * 128 + c) * 25 + tap]);
  } else {
    int j = idx - 204800;
    if (j < 4096) {
      int k   = j & 31;
      int lr  = (j >> 5) & 15;
      int oct = j >> 9;
      int oc  = oct * 16 + lr;
      float v = (k < 25) ? w1[oc * 25 + k] : 0.f;
      w1b[j] = __float2bfloat16(v);
    }
  }
}

// ---------------------------------------------------------------------------
// Fused conv1 (MFMA, xs staged bf16) -> h1 LDS bf16 (Gray-code swizzle)
// -> conv2 (MFMA, 4-wave K-split) -> BN2+LReLU+L2norm -> db.
// ---------------------------------------------------------------------------
__global__ __launch_bounds__(256) void k_conv(
    const float* __restrict__ x,
    const __hip_bfloat16* __restrict__ w1bh, const float* __restrict__ b1,
    const float* __restrict__ g1,  const float* __restrict__ be1,
    const float* __restrict__ mn1, const float* __restrict__ vr1,
    const __hip_bfloat16* __restrict__ w2bh, const float* __restrict__ b2,
    const float* __restrict__ g2,  const float* __restrict__ be2,
    const float* __restrict__ mn2, const float* __restrict__ vr2,
    __hip_bfloat16* __restrict__ db) {
  __shared__ unsigned short xsb[1024];              // padded 32x32 image, bf16
  __shared__ float nrm[4];
  __shared__ __align__(16) __hip_bfloat16 h1s[197 * 128];  // 50432 B

  const int t    = threadIdx.x;
  const int img  = blockIdx.x;
  const int lane = t & 63;
  const int wv   = t >> 6;
  const int lr   = lane & 15;
  const int kg   = lane >> 4;
  const short* w2b = (const short*)w2bh;
  const short* w1b = (const short*)w1bh;

  float a1v[8], s1v[8];
#pragma unroll
  for (int r = 0; r < 4; ++r) {
    int oc = wv * 32 + kg * 4 + r;
    float a = g1[oc] * rsqrtf(vr1[oc] + BN_EPS);
    a1v[r] = a; s1v[r] = b1[oc] * a + be1[oc] - mn1[oc] * a;
    int oc2 = oc + 16;
    float a2_ = g1[oc2] * rsqrtf(vr1[oc2] + BN_EPS);
    a1v[4 + r] = a2_; s1v[4 + r] = b1[oc2] * a2_ + be1[oc2] - mn1[oc2] * a2_;
  }
  float a2v[4], s2v[4];
#pragma unroll
  for (int r = 0; r < 4; ++r) {
    int oc = wv * 16 + kg * 4 + r;
    float a = g2[oc] * rsqrtf(vr2[oc] + BN_EPS);
    a2v[r] = a; s2v[r] = b2[oc] * a + be2[oc] - mn2[oc] * a;
  }

  for (int i = t; i < 1024; i += 256) xsb[i] = 0;
  if (t < 64) ((unsigned*)(h1s + 196 * 128))[t] = 0u;   // zero row 196 (full 256B)
  __syncthreads();
  const float* xi = x + (size_t)img * 784;
  for (int i = t; i < 784; i += 256) {
    int yy = i / 28, xx = i % 28;
    xsb[(yy + 2) * 32 + (xx + 2)] = (unsigned short)f2b(xi[i]);
  }
  __syncthreads();

  // ---- conv1 via MFMA: wave wv owns oc-tiles {2wv, 2wv+1}, 13 px tiles ----
  {
    bf16x8 a0 = *(const bf16x8*)(w1b + (2 * wv) * 512 + lr * 32 + kg * 8);
    bf16x8 a1 = *(const bf16x8*)(w1b + (2 * wv + 1) * 512 + lr * 32 + kg * 8);
    for (int pt = 0; pt < 13; ++pt) {
      const int px  = pt * 16 + lr;
      const int pxc = (px < 196) ? px : 195;
      const int oy  = pxc / 14, ox = pxc - 14 * (pxc / 14);
      const unsigned short* xb = xsb + (2 * oy) * 32 + 2 * ox;
      short bs[8];
#pragma unroll
      for (int j = 0; j < 8; ++j) {
        int k   = kg * 8 + j;
        int tap = (k < 25) ? k : 0;
        int kh  = tap / 5, kw = tap - 5 * (tap / 5);
        bs[j] = (short)xb[kh * 32 + kw];
      }
      bf16x8 b;
#pragma unroll
      for (int j = 0; j < 8; ++j) b[j] = bs[j];
      f32x4 c0 = {0.f, 0.f, 0.f, 0.f}, c1 = {0.f, 0.f, 0.f, 0.f};
      c0 = __builtin_amdgcn_mfma_f32_16x16x32_bf16(a0, b, c0, 0, 0, 0);
      c1 = __builtin_amdgcn_mfma_f32_16x16x32_bf16(a1, b, c1, 0, 0, 0);
      if (px < 196) {
        const int swz = swz8(px);
        float v[4], u[4];
#pragma unroll
        for (int r = 0; r < 4; ++r) {
          float h = c0[r] * a1v[r] + s1v[r];
          v[r] = (h >= 0.f) ? h : SLOPE * h;
          float h2 = c1[r] * a1v[4 + r] + s1v[4 + r];
          u[r] = (h2 >= 0.f) ? h2 : SLOPE * h2;
        }
        unsigned w0lo = (unsigned)(unsigned short)f2b(v[0]) |
                        ((unsigned)(unsigned short)f2b(v[1]) << 16);
        unsigned w0hi = (unsigned)(unsigned short)f2b(v[2]) |
                        ((unsigned)(unsigned short)f2b(v[3]) << 16);
        unsigned w1lo = (unsigned)(unsigned short)f2b(u[0]) |
                        ((unsigned)(unsigned short)f2b(u[1]) << 16);
        unsigned w1hi = (unsigned)(unsigned short)f2b(u[2]) |
                        ((unsigned)(unsigned short)f2b(u[3]) << 16);
        char* base = (char*)h1s + px * 256;
        const int o0 = ((wv * 32 + kg * 4) * 2) ^ swz;
        const int o1 = ((wv * 32 + 16 + kg * 4) * 2) ^ swz;
        *(uint2*)(base + o0) = make_uint2(w0lo, w0hi);
        *(uint2*)(base + o1) = make_uint2(w1lo, w1hi);
      }
    }
  }
  __syncthreads();

  // ---- conv2 MFMA: A = w2b, B = h1s, 4-way K-split ----
  const int woff  = lr * 32 + kg * 8;
  const int kgoff = kg << 4;
  int pxA[4], oyA[4], oxA[4];
#pragma unroll
  for (int pt = 0; pt < 4; ++pt) {
    int p = pt * 16 + lr;
    pxA[pt] = p;
    oyA[pt] = p / 7;
    oxA[pt] = p - 7 * oyA[pt];
  }

  f32x4 acc[4][4];
#pragma unroll
  for (int oct = 0; oct < 4; ++oct)
#pragma unroll
    for (int pt = 0; pt < 4; ++pt) acc[oct][pt] = (f32x4){0.f, 0.f, 0.f, 0.f};

  const int s0 = 25 * wv, s1e = s0 + 25;
  int curtap = -1;
  int rowB[4], rowS[4];

  auto loadk = [&](int kk, bf16x8* areg, bf16x8* breg) {
    int tap = kk >> 2;
    if (tap != curtap) {
      curtap = tap;
      int kh = tap / 5, kw = tap - 5 * (tap / 5);
#pragma unroll
      for (int pt = 0; pt < 4; ++pt) {
        int iy = 2 * oyA[pt] - 2 + kh;
        int ix = 2 * oxA[pt] - 2 + kw;
        bool val = (pxA[pt] < 49) & ((unsigned)iy < 14u) & ((unsigned)ix < 14u);
        int ip = val ? iy * 14 + ix : 196;
        rowB[pt] = ip * 256;
        rowS[pt] = swz8(ip);
      }
    }
    int c01 = (kk & 3) << 6;
#pragma unroll
    for (int oct = 0; oct < 4; ++oct)
      areg[oct] = *(const bf16x8*)(w2b + ((oct * 100 + kk) << 9) + woff);
#pragma unroll
    for (int pt = 0; pt < 4; ++pt)
      breg[pt] = *(const bf16x8*)((const char*)h1s + rowB[pt] +
                                  ((c01 | kgoff) ^ rowS[pt]));
  };

  bf16x8 a[4], b[4], an[4], bn_[4];
  loadk(s0, a, b);
  for (int kk = s0; kk < s1e; ++kk) {
    if (kk + 1 < s1e) loadk(kk + 1, an, bn_);
#pragma unroll
    for (int oct = 0; oct < 4; ++oct)
#pragma unroll
      for (int pt = 0; pt < 4; ++pt)
        acc[oct][pt] = __builtin_amdgcn_mfma_f32_16x16x32_bf16(a[oct], b[pt],
                                                               acc[oct][pt], 0, 0, 0);
#pragma unroll
    for (int q = 0; q < 4; ++q) { a[q] = an[q]; b[q] = bn_[q]; }
  }
  __syncthreads();

  float* red = (float*)h1s;
  if (wv != 0) {
#pragma unroll
    for (int oct = 0; oct < 4; ++oct)
#pragma unroll
      for (int pt = 0; pt < 4; ++pt)
#pragma unroll
        for (int r = 0; r < 4; ++r)
          red[(wv - 1) * 4096 + ((oct * 4 + pt) * 4 + r) * 64 + lane] =
              acc[oct][pt][r];
  }
  __syncthreads();
  if (wv == 0) {
#pragma unroll
    for (int oct = 0; oct < 4; ++oct)
#pragma unroll
      for (int pt = 0; pt < 4; ++pt)
#pragma unroll
        for (int r = 0; r < 4; ++r) {
          const int i = (oct * 4 + pt) * 4 + r;
          float v = acc[oct][pt][r] + red[i * 64 + lane] +
                    red[4096 + i * 64 + lane] + red[8192 + i * 64 + lane];
          red[i * 64 + lane] = v;
        }
  }
  __syncthreads();

  float outv[16];
  float ss = 0.f;
#pragma unroll
  for (int pt = 0; pt < 4; ++pt) {
#pragma unroll
    for (int r = 0; r < 4; ++r) {
      const int i = ((wv * 4 + pt) * 4 + r);
      float v = red[i * 64 + lane];
      v = v * a2v[r] + s2v[r];
      v = (v >= 0.f) ? v : SLOPE * v;
      outv[pt * 4 + r] = v;
      if (pxA[pt] < 49) ss += v * v;
    }
  }
#pragma unroll
  for (int m = 1; m < 64; m <<= 1) ss += __shfl_xor(ss, m, 64);
  if (lane == 0) nrm[wv] = ss;
  __syncthreads();
  const float invn = rsqrtf(nrm[0] + nrm[1] + nrm[2] + nrm[3]);
  __hip_bfloat16* dro = db + (size_t)img * DDIM;
#pragma unroll
  for (int pt = 0; pt < 4; ++pt) {
    if (pxA[pt] < 49) {
#pragma unroll
      for (int r = 0; r < 4; ++r) {
        const int oc = wv * 16 + kg * 4 + r;
        dro[oc * 49 + pxA[pt]] = __float2bfloat16(outv[pt * 4 + r] * invn);
      }
    }
  }
}

// ---------------------------------------------------------------------------
// 64x64 tiled transpose: dT[d][img] = db[img][d]   (NT both streams)
// ---------------------------------------------------------------------------
__global__ __launch_bounds__(256) void k_tr(const __hip_bfloat16* __restrict__ dbh,
                                            __hip_bfloat16* __restrict__ dTh) {
  __shared__ short tile[64][72];
  const int t   = threadIdx.x;
  const int i   = t >> 2;
  const int seg = t & 3;
  const size_t img0 = (size_t)blockIdx.x * 64;
  const size_t d0   = (size_t)blockIdx.y * 64;
  const short* src = (const short*)dbh + (img0 + i) * DDIM + d0 + seg * 16;
  bf16x8 v0 = __builtin_nontemporal_load((const bf16x8*)src);
  bf16x8 v1 = __builtin_nontemporal_load((const bf16x8*)(src + 8));
  *(bf16x8*)&tile[i][seg * 16]     = v0;
  *(bf16x8*)&tile[i][seg * 16 + 8] = v1;
  __syncthreads();
  short tmp[16];
#pragma unroll
  for (int k = 0; k < 16; ++k) tmp[k] = tile[seg * 16 + k][i];
  short* dst = (short*)dTh + (d0 + i) * 8192 + img0 + seg * 16;
  __builtin_nontemporal_store(*(bf16x8*)tmp, (bf16x8*)dst);
  __builtin_nontemporal_store(*((bf16x8*)tmp + 1), (bf16x8*)(dst + 8));
}

// ---------------------------------------------------------------------------
// mu bf16 init (rows 100-111 zero) + rT pad rows + crb zero.
// ---------------------------------------------------------------------------
__global__ __launch_bounds__(256) void k_muinit(const float* __restrict__ mu0,
                                                __hip_bfloat16* __restrict__ mub,
                                                __hip_bfloat16* __restrict__ rT,
                                                float* __restrict__ crb) {
  int idx = blockIdx.x * 256 + threadIdx.x;
  if (idx < 112 * DDIM) {
    int j = idx / DDIM, d = idx - j * DDIM;
    float v = (j < 100) ? mu0[j * DDIM + d] : 0.f;
    mub[idx] = __float2bfloat16(v);
  }
  if (idx < 12 * 8192)
    rT[(size_t)100 * 8192 + idx] = __float2bfloat16(0.f);
  if (idx < 12 * 128) crb[idx] = 0.f;
}

// ---------------------------------------------------------------------------
// Fused dist (MFMA) + softmax + cluster_r.  (r5/r10 shape: 512 blocks x 512
// thr, 16 rows, 8-way K-split.)  NT loads on data stream; packed rT stores.
// ---------------------------------------------------------------------------
__global__ __launch_bounds__(512) void k_dsm(
    const __hip_bfloat16* __restrict__ data,
    const __hip_bfloat16* __restrict__ mu,
    __hip_bfloat16* __restrict__ rT,          // [112][8192]
    float* __restrict__ cr,                   // [128] slot for this iter
    float* __restrict__ outr,                 // final: [8192][100]
    float* __restrict__ outd,                 // final: [8192][100]
    int final_flag) {
  __shared__ float red[7][64][29];
  const int t    = threadIdx.x;
  const int lane = t & 63;
  const int wv   = t >> 6;                    // 0..7
  const int rowbase = blockIdx.x * 16;
  const int s0 = (98 * wv) >> 3;
  const int s1 = (98 * (wv + 1)) >> 3;
  const int lr = lane & 15;
  const int kg = lane >> 4;

  const __hip_bfloat16* arow = data + (size_t)(rowbase + lr) * DDIM + kg * 8;
  const __hip_bfloat16* brow = mu + (size_t)lr * DDIM + kg * 8;

  f32x4 acc[7];
#pragma unroll
  for (int i = 0; i < 7; ++i) acc[i] = (f32x4){0.f, 0.f, 0.f, 0.f};

  bf16x8 a, b[7], an, bn_[7];
  {
    const int k0 = s0 * 32;
    a = __builtin_nontemporal_load((const bf16x8*)(arow + k0));
#pragma unroll
    for (int tl = 0; tl < 7; ++tl)
      b[tl] = *(const bf16x8*)(brow + (size_t)tl * 16 * DDIM + k0);
  }
  for (int s = s0; s < s1; ++s) {
    if (s + 1 < s1) {
      const int k1 = (s + 1) * 32;
      an = __builtin_nontemporal_load((const bf16x8*)(arow + k1));
#pragma unroll
      for (int tl = 0; tl < 7; ++tl)
        bn_[tl] = *(const bf16x8*)(brow + (size_t)tl * 16 * DDIM + k1);
    }
#pragma unroll
    for (int tl = 0; tl < 7; ++tl)
      acc[tl] = __builtin_amdgcn_mfma_f32_16x16x32_bf16(a, b[tl], acc[tl], 0, 0, 0);
    a = an;
#pragma unroll
    for (int tl = 0; tl < 7; ++tl) b[tl] = bn_[tl];
  }

  if (wv != 0) {
#pragma unroll
    for (int tl = 0; tl < 7; ++tl)
#pragma unroll
      for (int r = 0; r < 4; ++r) red[wv - 1][lane][tl * 4 + r] = acc[tl][r];
  }
  __syncthreads();
  if (wv != 0) return;

#pragma unroll
  for (int tl = 0; tl < 7; ++tl)
#pragma unroll
    for (int r = 0; r < 4; ++r) {
      float v = acc[tl][r];
#pragma unroll
      for (int bk = 0; bk < 7; ++bk) v += red[bk][lane][tl * 4 + r];
      acc[tl][r] = v;
    }

  if (final_flag) {
#pragma unroll
    for (int tl = 0; tl < 7; ++tl) {
      const int col = tl * 16 + lr;
      if (col < 100) {
#pragma unroll
        for (int r = 0; r < 4; ++r)
          outd[(size_t)(rowbase + kg * 4 + r) * 100 + col] = acc[tl][r];
      }
    }
  }

#pragma unroll
  for (int r = 0; r < 4; ++r) {
    float m = -1e30f;
#pragma unroll
    for (int tl = 0; tl < 7; ++tl) {
      const bool valid = (tl < 6) || (lr < 4);
      m = fmaxf(m, valid ? acc[tl][r] : -1e30f);
    }
    m = fmaxf(m, __shfl_xor(m, 1, 64));
    m = fmaxf(m, __shfl_xor(m, 2, 64));
    m = fmaxf(m, __shfl_xor(m, 4, 64));
    m = fmaxf(m, __shfl_xor(m, 8, 64));
    float s = 0.f;
    float e[7];
#pragma unroll
    for (int tl = 0; tl < 7; ++tl) {
      const bool valid = (tl < 6) || (lr < 4);
      e[tl] = valid ? __expf(TEMP * (acc[tl][r] - m)) : 0.f;
      s += e[tl];
    }
    s += __shfl_xor(s, 1, 64);
    s += __shfl_xor(s, 2, 64);
    s += __shfl_xor(s, 4, 64);
    s += __shfl_xor(s, 8, 64);
    const float inv = 1.f / s;
#pragma unroll
    for (int tl = 0; tl < 7; ++tl) acc[tl][r] = e[tl] * inv;
  }

  if (final_flag) {
#pragma unroll
    for (int tl = 0; tl < 7; ++tl) {
      const int col = tl * 16 + lr;
      if (col < 100) {
#pragma unroll
        for (int r = 0; r < 4; ++r)
          outr[(size_t)(rowbase + kg * 4 + r) * 100 + col] = acc[tl][r];
      }
    }
    return;
  }

#pragma unroll
  for (int tl = 0; tl < 7; ++tl) {
    const int col = tl * 16 + lr;
    if (col < 100) {
      unsigned lo = (unsigned)(unsigned short)f2b(acc[tl][0]) |
                    ((unsigned)(unsigned short)f2b(acc[tl][1]) << 16);
      unsigned hi = (unsigned)(unsigned short)f2b(acc[tl][2]) |
                    ((unsigned)(unsigned short)f2b(acc[tl][3]) << 16);
      *(uint2*)((short*)rT + (size_t)col * 8192 + rowbase + kg * 4) =
          make_uint2(lo, hi);
    }
  }
  float csum[7];
#pragma unroll
  for (int tl = 0; tl < 7; ++tl) {
    float cs = acc[tl][0] + acc[tl][1] + acc[tl][2] + acc[tl][3];
    cs += __shfl_xor(cs, 16, 64);
    cs += __shfl_xor(cs, 32, 64);
    csum[tl] = cs;
  }
  if (lane < 16) {
#pragma unroll
    for (int tl = 0; tl < 7; ++tl) {
      const int col = tl * 16 + lane;
      if (col < 100) atomicAdd(cr + col, csum[tl]);
    }
  }
}

// ---------------------------------------------------------------------------
// cms[split][d][j] (bf16) = partial dataT @ rT over K-chunk of 512.
// grid (49, 16); block = 64 d-rows (4 waves x 16 rows).  (r10 version)
// ---------------------------------------------------------------------------
__global__ __launch_bounds__(256) void k_mu(
    const __hip_bfloat16* __restrict__ dataT,  // [3136][8192]
    const __hip_bfloat16* __restrict__ rT,     // [112][8192]
    __hip_bfloat16* __restrict__ cms) {        // [16][3136][112]
  const int t    = threadIdx.x;
  const int lane = t & 63;
  const int wv   = t >> 6;
  const int mbase = blockIdx.x * 64 + wv * 16;
  const int kbase = blockIdx.y * 512;
  const int lr = lane & 15;
  const int kg = lane >> 4;

  const __hip_bfloat16* arow = dataT + (size_t)(mbase + lr) * 8192 + kbase + kg * 8;
  const __hip_bfloat16* brow = rT + (size_t)lr * 8192 + kbase + kg * 8;

  f32x4 acc[7];
#pragma unroll
  for (int i = 0; i < 7; ++i) acc[i] = (f32x4){0.f, 0.f, 0.f, 0.f};

  bf16x8 a, b[7], an, bn_[7];
  a = __builtin_nontemporal_load((const bf16x8*)arow);
#pragma unroll
  for (int tl = 0; tl < 7; ++tl)
    b[tl] = *(const bf16x8*)(brow + (size_t)tl * 16 * 8192);
  for (int s = 0; s < 16; ++s) {
    if (s + 1 < 16) {
      const int k1 = (s + 1) * 32;
      an = __builtin_nontemporal_load((const bf16x8*)(arow + k1));
#pragma unroll
      for (int tl = 0; tl < 7; ++tl)
        bn_[tl] = *(const bf16x8*)(brow + (size_t)tl * 16 * 8192 + k1);
    }
#pragma unroll
    for (int tl = 0; tl < 7; ++tl)
      acc[tl] = __builtin_amdgcn_mfma_f32_16x16x32_bf16(a, b[tl], acc[tl], 0, 0, 0);
    a = an;
#pragma unroll
    for (int tl = 0; tl < 7; ++tl) b[tl] = bn_[tl];
  }

  __hip_bfloat16* dst = cms + (size_t)blockIdx.y * (3136u * 112u);
#pragma unroll
  for (int tl = 0; tl < 7; ++tl) {
    const int col = tl * 16 + lr;
#pragma unroll
    for (int r = 0; r < 4; ++r)
      dst[(size_t)(mbase + kg * 4 + r) * 112 + col] = __float2bfloat16(acc[tl][r]);
  }
}

// ---------------------------------------------------------------------------
// Reduce 16 cms splits + LDS transpose + divide by cr. grid 196 (16 d each).
// Writes mub (bf16) and muf (fp32 -> d_out every iter; last write wins).
// ---------------------------------------------------------------------------
__global__ __launch_bounds__(256) void k_upd(const __hip_bfloat16* __restrict__ cms,
                                             const float* __restrict__ cr,
                                             float* __restrict__ muf,
                                             __hip_bfloat16* __restrict__ mub) {
  __shared__ float tile[16][113];
  const int t  = threadIdx.x;
  const int d0 = blockIdx.x * 16;
  for (int e = t; e < 16 * 112; e += 256) {
    int dd = e / 112, jj = e - dd * 112;
    const __hip_bfloat16* p = cms + (size_t)(d0 + dd) * 112 + jj;
    float v = 0.f;
#pragma unroll
    for (int s2 = 0; s2 < 16; ++s2)
      v += __bfloat162float(p[(size_t)s2 * (3136u * 112u)]);
    tile[dd][jj] = v;
  }
  __syncthreads();
  for (int e = t; e < 100 * 16; e += 256) {
    int jj = e >> 4, dd = e & 15;
    float v = tile[dd][jj] / cr[jj];
    muf[(size_t)jj * DDIM + d0 + dd] = v;
    mub[(size_t)jj * DDIM + d0 + dd] = __float2bfloat16(v);
  }
}

// ---------------------------------------------------------------------------
extern "C" void kernel_launch(void* const* d_in, const int* in_sizes, int n_in,
                              void* d_out, int out_size, void* d_ws, size_t ws_size,
                              hipStream_t stream) {
  const float* x   = (const float*)d_in[0];
  const float* w1  = (const float*)d_in[1];
  const float* b1  = (const float*)d_in[2];
  const float* g1  = (const float*)d_in[3];
  const float* be1 = (const float*)d_in[4];
  const float* mn1 = (const float*)d_in[5];
  const float* vr1 = (const float*)d_in[6];
  const float* w2  = (const float*)d_in[7];
  const float* b2  = (const float*)d_in[8];
  const float* g2  = (const float*)d_in[9];
  const float* be2 = (const float*)d_in[10];
  const float* mn2 = (const float*)d_in[11];
  const float* vr2 = (const float*)d_in[12];
  const float* mu0 = (const float*)d_in[13];

  float* ws = (float*)d_ws;
  __hip_bfloat16* w2b = (__hip_bfloat16*)(ws + W2B_OFF);
  __hip_bfloat16* w1b = (__hip_bfloat16*)(ws + W1B_OFF);
  __hip_bfloat16* db  = (__hip_bfloat16*)(ws + DB_OFF);
  __hip_bfloat16* dT  = (__hip_bfloat16*)(ws + DT_OFF);
  __hip_bfloat16* mub = (__hip_bfloat16*)(ws + MUB_OFF);
  __hip_bfloat16* cms = (__hip_bfloat16*)(ws + CMS_OFF);
  __hip_bfloat16* rT  = (__hip_bfloat16*)(ws + RT_OFF);
  float*          crb = ws + CRB_OFF;               // [12][128]
  float*          out = (float*)d_out;

  k_wprep<<<816, 256, 0, stream>>>(w2, w1, w2b, w1b);
  k_conv<<<8192, 256, 0, stream>>>(x, w1b, b1, g1, be1, mn1, vr1,
                                   w2b, b2, g2, be2, mn2, vr2, db);
  k_tr<<<dim3(128, 49), 256, 0, stream>>>(db, dT);
  k_muinit<<<1372, 256, 0, stream>>>(mu0, mub, rT, crb);

  for (int it = 0; it < 11; ++it) {
    k_dsm<<<512, 512, 0, stream>>>(db, mub, rT, crb + it * 128,
                                   nullptr, nullptr, 0);
    k_mu<<<dim3(49, 16), 256, 0, stream>>>(dT, rT, cms);
    k_upd<<<196, 256, 0, stream>>>(cms, crb + it * 128, out, mub);
  }

  k_dsm<<<512, 512, 0, stream>>>(db, mub, rT, crb + 11 * 128,
                                 out + 313600, out + 1132800, 1);
}